// Round 1
// baseline (230.333 us; speedup 1.0000x reference)
//
#include <hip/hip_runtime.h>
#include <math.h>

// Problem constants (match setup_inputs: B, N, D2, S = 64, 4096, 128, 512)
#define BB 64
#define NN 4096
#define DD 128
#define SS 512
#define CHUNKS 16
#define ROWS_PER_BLOCK 256  // NN / CHUNKS

// ---------------------------------------------------------------------------
// Kernel 1: q[b,e] = sum_d yq[b,d] * w[d,e]      (64 x 128 output, tiny)
// ---------------------------------------------------------------------------
__global__ void compute_q_kernel(const float* __restrict__ yq,
                                 const float* __restrict__ w,
                                 float* __restrict__ q) {
    int b = blockIdx.x;
    int e = threadIdx.x;  // 0..127
    __shared__ float syq[DD];
    syq[e] = yq[b * DD + e];
    __syncthreads();
    float acc = 0.f;
#pragma unroll
    for (int d = 0; d < DD; ++d) acc = fmaf(syq[d], w[d * DD + e], acc);
    q[b * DD + e] = acc;
}

// ---------------------------------------------------------------------------
// Kernel 2: logits[b,n] = q[b,:] . y_past[b,n,:]  + per-block max partials
// Wave-per-row: 64 lanes each load float2 (512 B per wave-instr, coalesced),
// butterfly reduce. grid = (B, CHUNKS), block = 256 (4 waves), 64 rows/wave.
// ---------------------------------------------------------------------------
__global__ void logits_kernel(const float* __restrict__ y_past,
                              const float* __restrict__ q,
                              float* __restrict__ logits,
                              float* __restrict__ pmax) {
    int b = blockIdx.x;
    int lane = threadIdx.x & 63;
    int wave = threadIdx.x >> 6;
    int n_base = blockIdx.y * ROWS_PER_BLOCK + wave * 64;

    float2 qv = ((const float2*)(q + b * DD))[lane];
    const float2* yp = (const float2*)(y_past + (size_t)b * NN * DD);

    float lmax = -1e30f;
    for (int i = 0; i < 64; ++i) {
        int n = n_base + i;
        float2 yv = yp[(size_t)n * 64 + lane];
        float p = fmaf(qv.x, yv.x, qv.y * yv.y);
#pragma unroll
        for (int off = 32; off > 0; off >>= 1) p += __shfl_xor(p, off, 64);
        // after butterfly, all lanes hold the full dot product
        if (lane == 0) logits[b * NN + n] = p;
        lmax = fmaxf(lmax, p);
    }

    __shared__ float smax[4];
    if (lane == 0) smax[wave] = lmax;
    __syncthreads();
    if (threadIdx.x == 0) {
        float m = fmaxf(fmaxf(smax[0], smax[1]), fmaxf(smax[2], smax[3]));
        pmax[b * CHUNKS + blockIdx.y] = m;
    }
}

// ---------------------------------------------------------------------------
// Kernel 3: per-b softmax + scatter into LDS bins, direct store of out[b,:].
// One block per b (512 threads) -> no global atomics, no output pre-zeroing.
// ---------------------------------------------------------------------------
__global__ void softmax_scatter_kernel(float* __restrict__ logits,
                                       const float* __restrict__ pmax,
                                       const int* __restrict__ s_past,
                                       float* __restrict__ out) {
    int b = blockIdx.x;
    int tid = threadIdx.x;  // 0..511
    __shared__ float bins[SS];
    __shared__ float red[8];
    __shared__ float s_m, s_inv;

    bins[tid] = 0.f;
    if (tid == 0) {
        float m = -1e30f;
        for (int c = 0; c < CHUNKS; ++c) m = fmaxf(m, pmax[b * CHUNKS + c]);
        s_m = m;
    }
    __syncthreads();

    float m = s_m;
    float lsum = 0.f;
#pragma unroll
    for (int k = 0; k < 8; ++k) {
        int n = tid + k * SS;
        float e = expf(logits[b * NN + n] - m);
        logits[b * NN + n] = e;  // stash exp for pass 2
        lsum += e;
    }
    // block reduction of sum: wave butterfly then across 8 waves
#pragma unroll
    for (int off = 32; off > 0; off >>= 1) lsum += __shfl_xor(lsum, off, 64);
    int lane = tid & 63, wave = tid >> 6;
    if (lane == 0) red[wave] = lsum;
    __syncthreads();
    if (tid == 0) {
        float s = 0.f;
        for (int w2 = 0; w2 < 8; ++w2) s += red[w2];
        s_inv = 1.0f / s;
    }
    __syncthreads();

    float inv = s_inv;
#pragma unroll
    for (int k = 0; k < 8; ++k) {
        int n = tid + k * SS;
        float a = logits[b * NN + n] * inv;
        atomicAdd(&bins[s_past[b * NN + n]], a);
    }
    __syncthreads();
    out[b * SS + tid] = bins[tid];
}

// ---------------------------------------------------------------------------
// Launch. Inputs: [0]=s_past (int, B*N), [1]=yq (f32, B*1*D2),
// [2]=y_past (f32, B*N*D2), [3]=w_mat (f32, D2*D2), [4]=size_s (int scalar).
// Output: post_est (f32, B*S). Workspace layout: q | logits | pmax.
// ---------------------------------------------------------------------------
extern "C" void kernel_launch(void* const* d_in, const int* in_sizes, int n_in,
                              void* d_out, int out_size, void* d_ws, size_t ws_size,
                              hipStream_t stream) {
    const int*   s_past = (const int*)d_in[0];
    const float* yq     = (const float*)d_in[1];
    const float* y_past = (const float*)d_in[2];
    const float* w_mat  = (const float*)d_in[3];

    float* ws     = (float*)d_ws;
    float* q      = ws;                    // B*DD          = 8192 floats
    float* logits = q + BB * DD;           // B*NN          = 262144 floats
    float* pmax   = logits + BB * NN;      // B*CHUNKS      = 1024 floats
    float* out    = (float*)d_out;

    compute_q_kernel<<<BB, DD, 0, stream>>>(yq, w_mat, q);
    logits_kernel<<<dim3(BB, CHUNKS), 256, 0, stream>>>(y_past, q, logits, pmax);
    softmax_scatter_kernel<<<BB, SS, 0, stream>>>(logits, pmax, s_past, out);
}

// Round 2
// 211.799 us; speedup vs baseline: 1.0875x; 1.0875x over previous
//
#include <hip/hip_runtime.h>
#include <math.h>

// Problem constants (B, N, D2, S = 64, 4096, 128, 512)
#define BB 64
#define NN 4096
#define DD 128
#define SS 512
#define CHUNKS 16          // blocks per b in logits kernel
#define ROWS_PER_CHUNK 256 // NN / CHUNKS
#define SUBT 4             // subtiles per chunk (64 rows each)

// ---------------------------------------------------------------------------
// Kernel 1: q[b,e] = sum_d yq[b,d] * w[d,e]   (tiny GEMV, 64x128 out)
// ---------------------------------------------------------------------------
__global__ void compute_q_kernel(const float* __restrict__ yq,
                                 const float* __restrict__ w,
                                 float* __restrict__ q) {
    int b = blockIdx.x;
    int e = threadIdx.x;  // 0..127
    __shared__ float syq[DD];
    syq[e] = yq[b * DD + e];
    __syncthreads();
    float acc = 0.f;
#pragma unroll
    for (int d = 0; d < DD; ++d) acc = fmaf(syq[d], w[d * DD + e], acc);
    q[b * DD + e] = acc;
}

// ---------------------------------------------------------------------------
// Kernel 2: logits[b,n] = q[b,:].y_past[b,n,:], plus per-chunk max and
// per-chunk sum(exp(logit - chunkmax)).
// grid (BB, CHUNKS), block 256. Each block: 256 rows in 4 subtiles of 64.
// Subtile: stage 64x128 floats to LDS (coalesced float4, padded stride 33
// float4s -> balanced banks), then 4 threads/row each dot 8 float4s,
// 2-shuffle reduce (vs 6 in R1 — that chain was the latency bottleneck).
// ---------------------------------------------------------------------------
__global__ __launch_bounds__(256) void logits_kernel(
    const float* __restrict__ y_past, const float* __restrict__ q,
    float* __restrict__ logits, float* __restrict__ pmax,
    float* __restrict__ psum) {
    int b = blockIdx.x, chunk = blockIdx.y;
    int t = threadIdx.x;

    __shared__ float4 ytile[64 * 33];  // 33792 B, padded row stride
    __shared__ float4 qsh4[32];
    __shared__ float wred[8];

    if (t < 32) qsh4[t] = ((const float4*)(q + b * DD))[t];
    __syncthreads();

    int j = t & 3;        // quarter of the row
    int r = t >> 2;       // row within subtile (0..63)
    float4 qreg[8];
#pragma unroll
    for (int k = 0; k < 8; ++k) qreg[k] = qsh4[j * 8 + k];

    const float4* gp =
        (const float4*)y_past + ((size_t)b * NN + (size_t)chunk * ROWS_PER_CHUNK) * 32;

    float pv[SUBT];
#pragma unroll
    for (int s = 0; s < SUBT; ++s) {
        // stage 64 rows (2048 float4s) cooperatively, coalesced
#pragma unroll
        for (int k = 0; k < 8; ++k) {
            int idx = t + k * 256;           // 0..2047
            int rr = idx >> 5, cc = idx & 31;
            ytile[rr * 33 + cc] = gp[s * 2048 + idx];
        }
        __syncthreads();

        float4 acc = {0.f, 0.f, 0.f, 0.f};
#pragma unroll
        for (int k = 0; k < 8; ++k) {
            float4 yv = ytile[r * 33 + j * 8 + k];
            acc.x = fmaf(qreg[k].x, yv.x, acc.x);
            acc.y = fmaf(qreg[k].y, yv.y, acc.y);
            acc.z = fmaf(qreg[k].z, yv.z, acc.z);
            acc.w = fmaf(qreg[k].w, yv.w, acc.w);
        }
        float p = (acc.x + acc.y) + (acc.z + acc.w);
        p += __shfl_xor(p, 1, 64);
        p += __shfl_xor(p, 2, 64);  // all 4 lanes of the group now hold full dot
        if (j == 0)
            logits[(size_t)b * NN + chunk * ROWS_PER_CHUNK + s * 64 + r] = p;
        pv[s] = p;
        __syncthreads();  // before next subtile overwrites ytile
    }

    // block max over the chunk's 256 rows
    float m = fmaxf(fmaxf(pv[0], pv[1]), fmaxf(pv[2], pv[3]));
#pragma unroll
    for (int off = 32; off > 0; off >>= 1) m = fmaxf(m, __shfl_xor(m, off, 64));
    int wave = t >> 6, lane = t & 63;
    if (lane == 0) wred[wave] = m;
    __syncthreads();
    m = fmaxf(fmaxf(wred[0], wred[1]), fmaxf(wred[2], wred[3]));

    // block sum of exp(p - m); each row appears in 4 lanes -> scale by 0.25
    float ls = __expf(pv[0] - m) + __expf(pv[1] - m) + __expf(pv[2] - m) +
               __expf(pv[3] - m);
#pragma unroll
    for (int off = 32; off > 0; off >>= 1) ls += __shfl_xor(ls, off, 64);
    if (lane == 0) wred[4 + wave] = ls;
    __syncthreads();
    if (t == 0) {
        pmax[b * CHUNKS + chunk] = m;
        psum[b * CHUNKS + chunk] =
            (wred[4] + wred[5] + wred[6] + wred[7]) * 0.25f;
    }
}

// ---------------------------------------------------------------------------
// Kernel 3: global softmax normalization (analytic from chunk max/sum) +
// scatter into LDS bins + direct store. One block per b, 1024 threads,
// single vectorized pass over logits. No global atomics, no out zeroing.
// ---------------------------------------------------------------------------
__global__ __launch_bounds__(1024) void scatter_kernel(
    const float* __restrict__ logits, const float* __restrict__ pmax,
    const float* __restrict__ psum, const int* __restrict__ s_past,
    float* __restrict__ out) {
    int b = blockIdx.x;
    int t = threadIdx.x;  // 0..1023
    __shared__ float bins[SS];
    __shared__ float cm[CHUNKS], cs[CHUNKS];
    __shared__ float sM, sInv;

    if (t < CHUNKS) {
        cm[t] = pmax[b * CHUNKS + t];
        cs[t] = psum[b * CHUNKS + t];
    }
    if (t < SS) bins[t] = 0.f;
    __syncthreads();
    if (t == 0) {
        float M = cm[0];
#pragma unroll
        for (int i = 1; i < CHUNKS; ++i) M = fmaxf(M, cm[i]);
        float S = 0.f;
#pragma unroll
        for (int i = 0; i < CHUNKS; ++i) S += cs[i] * __expf(cm[i] - M);
        sM = M;
        sInv = 1.f / S;
    }
    __syncthreads();

    float M = sM, inv = sInv;
    float4 lg = ((const float4*)(logits + (size_t)b * NN))[t];
    int4 sp = ((const int4*)(s_past + (size_t)b * NN))[t];
    atomicAdd(&bins[sp.x], __expf(lg.x - M) * inv);
    atomicAdd(&bins[sp.y], __expf(lg.y - M) * inv);
    atomicAdd(&bins[sp.z], __expf(lg.z - M) * inv);
    atomicAdd(&bins[sp.w], __expf(lg.w - M) * inv);
    __syncthreads();
    if (t < SS) out[b * SS + t] = bins[t];
}

// ---------------------------------------------------------------------------
// Launch. Inputs: [0]=s_past(int B*N), [1]=yq(f32 B*D2), [2]=y_past(f32
// B*N*D2), [3]=w_mat(f32 D2*D2), [4]=size_s. Out: post_est f32 B*S.
// ws: q | logits | pmax | psum
// ---------------------------------------------------------------------------
extern "C" void kernel_launch(void* const* d_in, const int* in_sizes, int n_in,
                              void* d_out, int out_size, void* d_ws, size_t ws_size,
                              hipStream_t stream) {
    const int*   s_past = (const int*)d_in[0];
    const float* yq     = (const float*)d_in[1];
    const float* y_past = (const float*)d_in[2];
    const float* w_mat  = (const float*)d_in[3];

    float* ws     = (float*)d_ws;
    float* q      = ws;                       // 8192
    float* logits = q + BB * DD;              // 262144
    float* pmax   = logits + BB * NN;         // 1024
    float* psum   = pmax + BB * CHUNKS;       // 1024
    float* out    = (float*)d_out;

    compute_q_kernel<<<BB, DD, 0, stream>>>(yq, w_mat, q);
    logits_kernel<<<dim3(BB, CHUNKS), 256, 0, stream>>>(y_past, q, logits,
                                                        pmax, psum);
    scatter_kernel<<<BB, 1024, 0, stream>>>(logits, pmax, psum, s_past, out);
}

// Round 3
// 204.885 us; speedup vs baseline: 1.1242x; 1.0337x over previous
//
#include <hip/hip_runtime.h>
#include <math.h>

// Problem constants (B, N, D2, S = 64, 4096, 128, 512)
#define BB 64
#define NN 4096
#define DD 128
#define SS 512
#define CHUNKS 16          // blocks per b
#define RPC 256            // rows per chunk = NN / CHUNKS
#define SUBT 4             // 64-row subtiles per chunk

// ---------------------------------------------------------------------------
// Fused kernel: per (b, chunk) block of 256 threads:
//   1. compute q[b,:] = yq[b,:] @ w   (redundant per block; w is L2-resident)
//   2. stream 256 rows of y_past through padded LDS tile (R2's verified path),
//      4 threads/row dot product, 2-shuffle reduce
//   3. chunk max m_c, scatter exp(p - m_c) into LDS bins[512]
//   4. write bins + m_c to workspace.  s_c = sum(bins) -> not computed here.
// ---------------------------------------------------------------------------
__global__ __launch_bounds__(256) void fused_kernel(
    const float* __restrict__ y_past, const float* __restrict__ yq,
    const float* __restrict__ w, const int* __restrict__ s_past,
    float* __restrict__ bins_g, float* __restrict__ pmax) {
    int b = blockIdx.x, chunk = blockIdx.y;
    int t = threadIdx.x;

    __shared__ float4 ytile[64 * 33];  // 33792 B, padded row stride (bank-safe)
    __shared__ float syq[DD];
    __shared__ float qsh[DD];
    __shared__ float bins[SS];
    __shared__ int   ssh[RPC];
    __shared__ float wred[8];

    // ---- stage yq, s_past; zero bins ----
    if (t < DD) syq[t] = yq[b * DD + t];
    bins[t] = 0.f;
    bins[t + 256] = 0.f;
    ssh[t] = s_past[b * NN + chunk * RPC + t];
    __syncthreads();

    // ---- q = yq @ w (threads 0..127, one output column each) ----
    if (t < DD) {
        float acc = 0.f;
#pragma unroll
        for (int d = 0; d < DD; ++d) acc = fmaf(syq[d], w[d * DD + t], acc);
        qsh[t] = acc;
    }
    __syncthreads();

    int j = t & 3;   // quarter of row
    int r = t >> 2;  // row within subtile
    float4 qreg[8];
#pragma unroll
    for (int k = 0; k < 8; ++k) qreg[k] = ((const float4*)qsh)[j * 8 + k];

    const float4* gp =
        (const float4*)y_past + ((size_t)b * NN + (size_t)chunk * RPC) * 32;

    // ---- stream 4 subtiles of 64 rows ----
    float pv[SUBT];
#pragma unroll
    for (int s = 0; s < SUBT; ++s) {
#pragma unroll
        for (int k = 0; k < 8; ++k) {
            int idx = t + k * 256;  // 0..2047
            int rr = idx >> 5, cc = idx & 31;
            ytile[rr * 33 + cc] = gp[s * 2048 + idx];
        }
        __syncthreads();

        float4 acc = {0.f, 0.f, 0.f, 0.f};
#pragma unroll
        for (int k = 0; k < 8; ++k) {
            float4 yv = ytile[r * 33 + j * 8 + k];
            acc.x = fmaf(qreg[k].x, yv.x, acc.x);
            acc.y = fmaf(qreg[k].y, yv.y, acc.y);
            acc.z = fmaf(qreg[k].z, yv.z, acc.z);
            acc.w = fmaf(qreg[k].w, yv.w, acc.w);
        }
        float p = (acc.x + acc.y) + (acc.z + acc.w);
        p += __shfl_xor(p, 1, 64);
        p += __shfl_xor(p, 2, 64);  // all 4 lanes of row-group hold full dot
        pv[s] = p;
        __syncthreads();  // before next subtile overwrites ytile
    }

    // ---- chunk max over 256 rows ----
    float m = fmaxf(fmaxf(pv[0], pv[1]), fmaxf(pv[2], pv[3]));
#pragma unroll
    for (int off = 32; off > 0; off >>= 1) m = fmaxf(m, __shfl_xor(m, off, 64));
    int wave = t >> 6, lane = t & 63;
    if (lane == 0) wred[wave] = m;
    __syncthreads();
    m = fmaxf(fmaxf(wred[0], wred[1]), fmaxf(wred[2], wred[3]));

    // ---- scatter exp(p - m_c) into LDS bins (j==0 lane of each row group) ----
    if (j == 0) {
#pragma unroll
        for (int s = 0; s < SUBT; ++s)
            atomicAdd(&bins[ssh[s * 64 + r]], __expf(pv[s] - m));
    }
    __syncthreads();

    // ---- write chunk bins + max ----
    float* bg = bins_g + ((size_t)b * CHUNKS + chunk) * SS;
    bg[t] = bins[t];
    bg[t + 256] = bins[t + 256];
    if (t == 0) pmax[b * CHUNKS + chunk] = m;
}

// ---------------------------------------------------------------------------
// Combine: out[b,s] = (sum_c bins[b,c,s] * exp(m_c - M)) / S,
// S recovered as the block-wide sum of the numerators. 64 blocks x 512 thr.
// ---------------------------------------------------------------------------
__global__ __launch_bounds__(512) void combine_kernel(
    const float* __restrict__ bins_g, const float* __restrict__ pmax,
    float* __restrict__ out) {
    int b = blockIdx.x;
    int t = threadIdx.x;  // 0..511
    __shared__ float scale[CHUNKS];
    __shared__ float red[8];
    __shared__ float sInv;

    if (t < CHUNKS) scale[t] = pmax[b * CHUNKS + t];
    __syncthreads();
    if (t == 0) {
        float M = scale[0];
#pragma unroll
        for (int c = 1; c < CHUNKS; ++c) M = fmaxf(M, scale[c]);
#pragma unroll
        for (int c = 0; c < CHUNKS; ++c) scale[c] = __expf(scale[c] - M);
    }
    __syncthreads();

    float acc = 0.f;
#pragma unroll
    for (int c = 0; c < CHUNKS; ++c)
        acc = fmaf(bins_g[((size_t)b * CHUNKS + c) * SS + t], scale[c], acc);

    float s = acc;
#pragma unroll
    for (int off = 32; off > 0; off >>= 1) s += __shfl_xor(s, off, 64);
    if ((t & 63) == 0) red[t >> 6] = s;
    __syncthreads();
    if (t == 0) {
        float S = 0.f;
#pragma unroll
        for (int i = 0; i < 8; ++i) S += red[i];
        sInv = 1.f / S;
    }
    __syncthreads();

    out[b * SS + t] = acc * sInv;
}

// ---------------------------------------------------------------------------
// Launch. Inputs: [0]=s_past(int B*N), [1]=yq(f32 B*D2), [2]=y_past(f32
// B*N*D2), [3]=w_mat(f32 D2*D2), [4]=size_s. Out: post_est f32 B*S.
// ws: bins_g (B*CHUNKS*S = 2 MB) | pmax (B*CHUNKS)
// ---------------------------------------------------------------------------
extern "C" void kernel_launch(void* const* d_in, const int* in_sizes, int n_in,
                              void* d_out, int out_size, void* d_ws, size_t ws_size,
                              hipStream_t stream) {
    const int*   s_past = (const int*)d_in[0];
    const float* yq     = (const float*)d_in[1];
    const float* y_past = (const float*)d_in[2];
    const float* w_mat  = (const float*)d_in[3];

    float* ws     = (float*)d_ws;
    float* bins_g = ws;                         // BB*CHUNKS*SS floats
    float* pmax   = bins_g + BB * CHUNKS * SS;  // BB*CHUNKS floats
    float* out    = (float*)d_out;

    fused_kernel<<<dim3(BB, CHUNKS), 256, 0, stream>>>(y_past, yq, w_mat,
                                                       s_past, bins_g, pmax);
    combine_kernel<<<BB, SS, 0, stream>>>(bins_g, pmax, out);
}